// Round 6
// baseline (130.671 us; speedup 1.0000x reference)
//
#include <hip/hip_runtime.h>
#include <math.h>
#include <limits.h>

#define BB 4
#define SS 2048
#define HH 768
#define MAXSEG 256
#define NUM_POS (BB*(SS/4))   // 2048
#define PPB (SS/4)            // positives per batch = 512
#define NEG_BIG -1000000000.0f

typedef _Float16 f16x8 __attribute__((ext_vector_type(8)));
typedef _Float16 f16x4 __attribute__((ext_vector_type(4)));
typedef float    f32x4 __attribute__((ext_vector_type(4)));

// ---------------------------------------------------------------------------
// D1: blocks 0..3: per-batch scans (+ packed positive records).
//     Blocks 4..579: W f32->f16 cast.
// Records: int4 {si, sL, L, cL} per positive, in rank order — posfinal's
// 4-level dependent gather chain becomes 2 levels.
// ---------------------------------------------------------------------------
__global__ __launch_bounds__(256) void k_scanW(
    const int* __restrict__ ind, const int* __restrict__ clc,
    const float* __restrict__ W, _Float16* __restrict__ Wh,
    int* __restrict__ seg_start, int* __restrict__ nseg,
    int4* __restrict__ pos_rec, int* __restrict__ pos_cnt,
    int* __restrict__ allowCnt, int* __restrict__ firstAllow)
{
  int t = threadIdx.x;
  if (blockIdx.x >= BB) {
    int idx = (blockIdx.x - BB)*256 + t;     // float4 index; 147456 total
    float4 v = ((const float4*)W)[idx];
    f16x4 h;
    h[0] = (_Float16)v.x; h[1] = (_Float16)v.y;
    h[2] = (_Float16)v.z; h[3] = (_Float16)v.w;
    *(f16x4*)(Wh + (size_t)idx*4) = h;
    return;
  }
  int b = blockIdx.x;
  int lane = t & 63, wid = t >> 6;
  __shared__ int sInd[SS];
  __shared__ int sClc[SS];
  __shared__ int sSeg[SS];
  __shared__ int sWave[4];
  __shared__ int sAC[MAXSEG];
  __shared__ int sFA[MAXSEG];
  // vectorized staging of ind and clc (int4, fully coalesced)
  for (int i = t; i < SS/4; i += 256) {
    ((int4*)sInd)[i] = ((const int4*)(ind + b*SS))[i];
    ((int4*)sClc)[i] = ((const int4*)(clc + b*SS))[i];
  }
  sAC[t] = 0; sFA[t] = INT_MAX;
  __syncthreads();

  int i0 = t * 8;
  int f[8], cv[8];
  int lsum = 0;
  #pragma unroll
  for (int u = 0; u < 8; u++) {
    int i = i0 + u;
    f[u] = (i == 0) ? 0 : (sInd[i] != sInd[i-1]);
    cv[u] = sClc[i];
    lsum += f[u];
  }
  int x = lsum;
  #pragma unroll
  for (int off = 1; off < 64; off <<= 1) {
    int v = __shfl_up(x, off, 64);
    if (lane >= off) x += v;
  }
  if (lane == 63) sWave[wid] = x;
  __syncthreads();
  int base = 0;
  for (int w = 0; w < wid; w++) base += sWave[w];
  int run = base + x - lsum;
  int rid[8];
  #pragma unroll
  for (int u = 0; u < 8; u++) {
    int i = i0 + u;
    run += f[u];
    rid[u] = run;
    sSeg[i] = run;
    if (f[u] || i == 0) seg_start[b*(MAXSEG+1) + run] = i;
  }
  if (t == 255) { nseg[b] = run + 1; seg_start[b*(MAXSEG+1) + run + 1] = SS; }

  #pragma unroll
  for (int u = 0; u < 8; u++) {
    if (cv[u] < 0) {
      atomicAdd(&sAC[rid[u]], 1);
      atomicMin(&sFA[rid[u]], i0 + u);
    }
  }
  __syncthreads();                         // sSeg also complete past here
  allowCnt[b*MAXSEG + t]   = sAC[t];
  firstAllow[b*MAXSEG + t] = sFA[t];

  int psum = 0;
  int p[8];
  #pragma unroll
  for (int u = 0; u < 8; u++) { p[u] = (cv[u] > 0) ? 1 : 0; psum += p[u]; }
  x = psum;
  #pragma unroll
  for (int off = 1; off < 64; off <<= 1) {
    int v = __shfl_up(x, off, 64);
    if (lane >= off) x += v;
  }
  __syncthreads();
  if (lane == 63) sWave[wid] = x;
  __syncthreads();
  base = 0;
  for (int w = 0; w < wid; w++) base += sWave[w];
  int rank = base + x - psum;
  #pragma unroll
  for (int u = 0; u < 8; u++) {
    if (p[u]) {
      int L = cv[u];                       // label position, 1..SS-1
      int4 rec;
      rec.x = rid[u];                      // si  = segment of this position
      rec.y = sSeg[L];                     // sL  = segment of label position
      rec.z = L;                           // label position
      rec.w = sClc[L];                     // clc at label position (mask test)
      pos_rec[b*PPB + rank] = rec;
      rank++;
    }
  }
  if (t == 255) pos_cnt[b] = rank;
}

// ---------------------------------------------------------------------------
// D2: segment sums. 1024 threads/block: 4 groups of 256 threads, each group
// sums a contiguous quarter of the segment's rows (4-row unrolled), then a
// deterministic 4-way LDS combine. (verified round 5)
// ---------------------------------------------------------------------------
__global__ __launch_bounds__(1024) void k_segsum(
    const float* __restrict__ es,
    const int* __restrict__ seg_start, const int* __restrict__ nseg,
    _Float16* __restrict__ segsum_h)
{
  __shared__ float sP[4][HH];            // 12 KB
  int blk = blockIdx.x, t = threadIdx.x;
  int b = blk >> 8, s = blk & 255;
  _Float16* o = segsum_h + ((size_t)b*MAXSEG + s)*HH;
  if (s >= nseg[b]) {   // zero-fill missing segments (keep downstream NaN-free)
    if (t < HH) o[t] = (_Float16)0.f;
    return;
  }
  int g = t >> 8, tt = t & 255;          // group 0..3, col-thread 0..255
  int st = seg_start[b*(MAXSEG+1) + s];
  int en = seg_start[b*(MAXSEG+1) + s + 1];
  int len = en - st;
  int q = (len + 3) >> 2;                // rows per group (last may be short)
  int gs = st + g*q;
  int ge = gs + q; if (ge > en) ge = en;
  const float* base = es + (size_t)b*SS*HH;
  float a0 = 0.f, a1 = 0.f, a2 = 0.f;
  float b0 = 0.f, b1 = 0.f, b2 = 0.f;
  float c0 = 0.f, c1 = 0.f, c2 = 0.f;
  float d0 = 0.f, d1 = 0.f, d2 = 0.f;
  int i = gs;
  for (; i + 4 <= ge; i += 4) {
    const float* r0 = base + (size_t)i*HH;
    const float* r1 = r0 + HH;
    const float* r2 = r1 + HH;
    const float* r3 = r2 + HH;
    a0 += r0[tt]; a1 += r0[tt+256]; a2 += r0[tt+512];
    b0 += r1[tt]; b1 += r1[tt+256]; b2 += r1[tt+512];
    c0 += r2[tt]; c1 += r2[tt+256]; c2 += r2[tt+512];
    d0 += r3[tt]; d1 += r3[tt+256]; d2 += r3[tt+512];
  }
  for (; i < ge; i++) {
    const float* r = base + (size_t)i*HH;
    a0 += r[tt]; a1 += r[tt+256]; a2 += r[tt+512];
  }
  sP[g][tt]     = (a0 + b0) + (c0 + d0);
  sP[g][tt+256] = (a1 + b1) + (c1 + d1);
  sP[g][tt+512] = (a2 + b2) + (c2 + d2);
  __syncthreads();
  if (t < HH) {
    float v = (sP[0][t] + sP[1][t]) + (sP[2][t] + sP[3][t]);
    o[t] = (_Float16)v;
  }
}

// ---------------------------------------------------------------------------
// D3: U = tanh(segsum @ W^T + bias), f16 MFMA, direct-global fragments.
// 256 blocks x 3 waves = 768 tiles -> all 256 CUs active. (verified round 5)
// ---------------------------------------------------------------------------
__global__ __launch_bounds__(192) void k_gemmU(
    const _Float16* __restrict__ Ah, const _Float16* __restrict__ Wh,
    const float* __restrict__ bias, _Float16* __restrict__ Uh)
{
  int tid = threadIdx.x;
  int w = tid >> 6, lane = tid & 63;
  int tile = blockIdx.x*3 + w;          // 0..767 over 32 x 24 tiles
  int tm = tile / 24, tn = tile % 24;
  int rb = tm*32, cb = tn*32;
  int m0 = lane & 15, quad = lane >> 4;
  const _Float16* A0 = Ah + (size_t)(rb + m0)*HH + quad*8;
  const _Float16* A1 = A0 + (size_t)16*HH;
  const _Float16* B0 = Wh + (size_t)(cb + m0)*HH + quad*8;
  const _Float16* B1 = B0 + (size_t)16*HH;
  f32x4 acc00 = {0.f,0.f,0.f,0.f}, acc01 = {0.f,0.f,0.f,0.f};
  f32x4 acc10 = {0.f,0.f,0.f,0.f}, acc11 = {0.f,0.f,0.f,0.f};
  #pragma unroll 4
  for (int k0 = 0; k0 < HH; k0 += 32) {
    f16x8 a0 = *(const f16x8*)(A0 + k0);
    f16x8 a1 = *(const f16x8*)(A1 + k0);
    f16x8 b0 = *(const f16x8*)(B0 + k0);
    f16x8 b1 = *(const f16x8*)(B1 + k0);
    acc00 = __builtin_amdgcn_mfma_f32_16x16x32_f16(a0, b0, acc00, 0, 0, 0);
    acc01 = __builtin_amdgcn_mfma_f32_16x16x32_f16(a0, b1, acc01, 0, 0, 0);
    acc10 = __builtin_amdgcn_mfma_f32_16x16x32_f16(a1, b0, acc10, 0, 0, 0);
    acc11 = __builtin_amdgcn_mfma_f32_16x16x32_f16(a1, b1, acc11, 0, 0, 0);
  }
  float bc0 = bias[cb + m0], bc1 = bias[cb + 16 + m0];
  int r0 = rb + quad*4;
  #pragma unroll
  for (int i = 0; i < 4; i++) {
    Uh[(size_t)(r0+i)*HH    + cb + m0]      = (_Float16)tanhf(acc00[i] + bc0);
    Uh[(size_t)(r0+i)*HH    + cb + 16 + m0] = (_Float16)tanhf(acc01[i] + bc1);
    Uh[(size_t)(r0+16+i)*HH + cb + m0]      = (_Float16)tanhf(acc10[i] + bc0);
    Uh[(size_t)(r0+16+i)*HH + cb + 16 + m0] = (_Float16)tanhf(acc11[i] + bc1);
  }
}

// ---------------------------------------------------------------------------
// D4: fused Gram panel + row-LSE. Block = (b, 16-row panel), 1024 threads:
// 16 MFMA waves (4/SIMD — latency hidden, unlike the 1-wave/SIMD split gram),
// each computing one 16x16 tile, then LSE of its row from LDS.
// Identical per-row reduction order to the verified separate k_seglse.
// (this exact kernel passed in round 3)
// ---------------------------------------------------------------------------
__global__ __launch_bounds__(1024) void k_gramlse(
    const _Float16* __restrict__ Uh, const int* __restrict__ allowCnt,
    const int* __restrict__ firstAllow, const int* __restrict__ nseg,
    float* __restrict__ G, float* __restrict__ lse, int* __restrict__ amax)
{
  __shared__ float sG[16][257];          // +1 pad
  int t = threadIdx.x;
  int lane = t & 63, w = t >> 6;         // w = 0..15
  int blk = blockIdx.x;                  // 0..63
  int b = blk >> 4;
  int rb = (blk & 15) * 16;
  int m0 = lane & 15, quad = lane >> 4;
  const _Float16* Ub = Uh + (size_t)b*MAXSEG*HH;
  const _Float16* A0 = Ub + (size_t)(rb + m0)*HH + quad*8;
  int cb = w * 16;                       // this wave's col-tile
  const _Float16* B0 = Ub + (size_t)(cb + m0)*HH + quad*8;
  f32x4 acc = {0.f,0.f,0.f,0.f};
  #pragma unroll 4
  for (int k0 = 0; k0 < HH; k0 += 32) {
    f16x8 a  = *(const f16x8*)(A0 + k0);
    f16x8 bb = *(const f16x8*)(B0 + k0);
    acc = __builtin_amdgcn_mfma_f32_16x16x32_f16(a, bb, acc, 0, 0, 0);
  }
  float* Gb = G + (size_t)b*MAXSEG*MAXSEG;
  int r0 = quad*4;
  #pragma unroll
  for (int i = 0; i < 4; i++) {
    sG[r0 + i][cb + m0] = acc[i];
    Gb[(size_t)(rb + r0 + i)*MAXSEG + cb + m0] = acc[i];
  }
  __syncthreads();

  // ---- row LSE + argmax from LDS; wave w handles row rb+w ----
  int si = rb + w;
  if (si >= nseg[b]) return;
  const int* ac = allowCnt + b*MAXSEG;
  const int* fa = firstAllow + b*MAXSEG;
  float gv[4]; int av[4], fv[4];
  #pragma unroll
  for (int q = 0; q < 4; q++) {
    int s = lane + 64*q;
    gv[q] = sG[w][s]; av[q] = ac[s]; fv[q] = fa[s];
  }
  float m = -INFINITY;
  #pragma unroll
  for (int q = 0; q < 4; q++) if (av[q] > 0) m = fmaxf(m, gv[q]);
  #pragma unroll
  for (int off = 32; off > 0; off >>= 1) m = fmaxf(m, __shfl_xor(m, off, 64));
  float s = 0.f;
  #pragma unroll
  for (int q = 0; q < 4; q++) if (av[q] > 0) s += (float)av[q] * expf(gv[q] - m);
  #pragma unroll
  for (int off = 32; off > 0; off >>= 1) s += __shfl_xor(s, off, 64);
  float bv = -INFINITY; int bi = INT_MAX;
  #pragma unroll
  for (int q = 0; q < 4; q++) {
    if (av[q] > 0 && (gv[q] > bv || (gv[q] == bv && fv[q] < bi))) { bv = gv[q]; bi = fv[q]; }
  }
  #pragma unroll
  for (int off = 32; off > 0; off >>= 1) {
    float ov = __shfl_xor(bv, off, 64);
    int   oi = __shfl_xor(bi, off, 64);
    if (ov > bv || (ov == bv && oi < bi)) { bv = ov; bi = oi; }
  }
  if (lane == 0) {
    lse[b*MAXSEG + si]  = m + logf(s);
    amax[b*MAXSEG + si] = bi;
  }
}

// ---------------------------------------------------------------------------
// D5: single block — all positives via packed records (2-level gather:
// coalesced 16B record load -> G/lse/amax). Accumulation order unchanged.
// ---------------------------------------------------------------------------
__global__ __launch_bounds__(256) void k_posfinal(
    const float* __restrict__ G, const int4* __restrict__ pos_rec,
    const int* __restrict__ pos_cnt, const float* __restrict__ lse,
    const int* __restrict__ amax, float* __restrict__ out)
{
  __shared__ int sBase[BB+1];
  __shared__ float sL0[4], sC0[4], sL1[4], sC1[4];
  int t = threadIdx.x;
  if (t == 0) {
    int acc = 0; sBase[0] = 0;
    for (int b = 0; b < BB; b++) { acc += pos_cnt[b]; sBase[b+1] = acc; }
  }
  __syncthreads();
  int total = sBase[BB];
  if (total > NUM_POS) total = NUM_POS;

  int rs[8]; bool ok[8]; int bv[8];
  #pragma unroll
  for (int u = 0; u < 8; u++) {
    rs[u] = t + 256*u;
    ok[u] = rs[u] < total;
    int b = 0;
    if (ok[u]) { while (b < BB-1 && rs[u] >= sBase[b+1]) b++; }
    bv[u] = b;
  }
  int4 rec[8];
  #pragma unroll
  for (int u = 0; u < 8; u++) {
    rec[u] = ok[u] ? pos_rec[bv[u]*PPB + (rs[u] - sBase[bv[u]])]
                   : make_int4(0, 0, 0, 0);
  }
  float gv[8], lv[8]; int av[8];
  #pragma unroll
  for (int u = 0; u < 8; u++) {
    gv[u] = ok[u] ? G[((size_t)bv[u]*MAXSEG + rec[u].x)*MAXSEG + rec[u].y] : 0.f;
    lv[u] = ok[u] ? lse[bv[u]*MAXSEG + rec[u].x] : 0.f;
    av[u] = ok[u] ? amax[bv[u]*MAXSEG + rec[u].x] : -1;
  }

  float l0 = 0.f, c0 = 0.f, l1 = 0.f, c1 = 0.f;
  #pragma unroll
  for (int u = 0; u < 8; u++) {
    if (!ok[u]) continue;
    float vL = gv[u] + (rec[u].w < 0 ? 0.0f : NEG_BIG);
    float loss = lv[u] - vL;
    float corr = (av[u] == rec[u].z) ? 1.0f : 0.0f;
    if (rs[u] & 1) { l1 += loss; c1 += corr; } else { l0 += loss; c0 += corr; }
  }

  int lane = t & 63, wid = t >> 6;
  #pragma unroll
  for (int off = 32; off > 0; off >>= 1) {
    l0 += __shfl_down(l0, off, 64);
    c0 += __shfl_down(c0, off, 64);
    l1 += __shfl_down(l1, off, 64);
    c1 += __shfl_down(c1, off, 64);
  }
  if (lane == 0) { sL0[wid] = l0; sC0[wid] = c0; sL1[wid] = l1; sC1[wid] = c1; }
  __syncthreads();
  if (t == 0) {
    float L0 = sL0[0]+sL0[1]+sL0[2]+sL0[3];
    float C0 = sC0[0]+sC0[1]+sC0[2]+sC0[3];
    float L1 = sL1[0]+sL1[1]+sL1[2]+sL1[3];
    float C1 = sC1[0]+sC1[1]+sC1[2]+sC1[3];
    float n = (float)(NUM_POS/2);   // 1024
    out[0] = L0 / n;
    out[1] = C0;
    out[2] = n + 1e-6f;
    out[3] = L1 / n;
    out[4] = C1;
    out[5] = n + 1e-6f;
  }
}

// ---------------------------------------------------------------------------
extern "C" void kernel_launch(void* const* d_in, const int* in_sizes, int n_in,
                              void* d_out, int out_size, void* d_ws, size_t ws_size,
                              hipStream_t stream)
{
  const float* es   = (const float*)d_in[0];
  const float* W    = (const float*)d_in[1];
  const float* bias = (const float*)d_in[2];
  const int*   ind  = (const int*)d_in[3];
  const int*   clc  = (const int*)d_in[4];
  float* out = (float*)d_out;

  char* ws = (char*)d_ws;
  int*   nseg       = (int*)(ws + 0);
  int*   pos_cnt    = (int*)(ws + 256);
  int*   seg_start  = (int*)(ws + 1024);                 // B*(MAXSEG+1)
  int4*  pos_rec    = (int4*)(ws + 40960);               // B*512*16 = 32 KB
  int*   allowCnt   = (int*)(ws + 73728);                // B*256
  int*   firstAllow = (int*)(ws + 77824);
  float* lse        = (float*)(ws + 81920);
  int*   amax       = (int*)(ws + 86016);
  _Float16* segsum_h = (_Float16*)(ws + 90112);          // 1024*768*2 = 1.5 MB
  _Float16* Wh       = (_Float16*)(ws + 1662976);        // 768*768*2 = 1.125 MB
  _Float16* Uh       = (_Float16*)(ws + 2842624);        // 1.5 MB
  float*    G        = (float*)(ws + 4415488);           // 1 MB

  k_scanW<<<BB + 576, 256, 0, stream>>>(ind, clc, W, Wh, seg_start,
                                        nseg, pos_rec, pos_cnt, allowCnt, firstAllow);
  k_segsum<<<BB*MAXSEG, 1024, 0, stream>>>(es, seg_start, nseg, segsum_h);
  k_gemmU<<<256, 192, 0, stream>>>(segsum_h, Wh, bias, Uh);
  k_gramlse<<<BB*16, 1024, 0, stream>>>(Uh, allowCnt, firstAllow, nseg, G, lse, amax);
  k_posfinal<<<1, 256, 0, stream>>>(G, pos_rec, pos_cnt, lse, amax, out);
}

// Round 7
// 115.895 us; speedup vs baseline: 1.1275x; 1.1275x over previous
//
#include <hip/hip_runtime.h>
#include <math.h>
#include <limits.h>

#define BB 4
#define SS 2048
#define HH 768
#define MAXSEG 256
#define NUM_POS (BB*(SS/4))   // 2048
#define PPB (SS/4)            // positives per batch = 512
#define NEG_BIG -1000000000.0f

typedef _Float16 f16x8 __attribute__((ext_vector_type(8)));
typedef _Float16 f16x4 __attribute__((ext_vector_type(4)));
typedef float    f32x4 __attribute__((ext_vector_type(4)));

// ---------------------------------------------------------------------------
// D1: blocks 0..3: per-batch scans (+ packed positive records).
//     Blocks 4..579: W f32->f16 cast.
// Records: int4 {si, sL, L, cL} per positive, in rank order — posfinal's
// gather chain is 2 levels (record -> G/lse/amax). Verified round 6.
// ---------------------------------------------------------------------------
__global__ __launch_bounds__(256) void k_scanW(
    const int* __restrict__ ind, const int* __restrict__ clc,
    const float* __restrict__ W, _Float16* __restrict__ Wh,
    int* __restrict__ seg_start, int* __restrict__ nseg,
    int4* __restrict__ pos_rec, int* __restrict__ pos_cnt,
    int* __restrict__ allowCnt, int* __restrict__ firstAllow)
{
  int t = threadIdx.x;
  if (blockIdx.x >= BB) {
    int idx = (blockIdx.x - BB)*256 + t;     // float4 index; 147456 total
    float4 v = ((const float4*)W)[idx];
    f16x4 h;
    h[0] = (_Float16)v.x; h[1] = (_Float16)v.y;
    h[2] = (_Float16)v.z; h[3] = (_Float16)v.w;
    *(f16x4*)(Wh + (size_t)idx*4) = h;
    return;
  }
  int b = blockIdx.x;
  int lane = t & 63, wid = t >> 6;
  __shared__ int sInd[SS];
  __shared__ int sClc[SS];
  __shared__ int sSeg[SS];
  __shared__ int sWave[4];
  __shared__ int sAC[MAXSEG];
  __shared__ int sFA[MAXSEG];
  // vectorized staging of ind and clc (int4, fully coalesced)
  for (int i = t; i < SS/4; i += 256) {
    ((int4*)sInd)[i] = ((const int4*)(ind + b*SS))[i];
    ((int4*)sClc)[i] = ((const int4*)(clc + b*SS))[i];
  }
  sAC[t] = 0; sFA[t] = INT_MAX;
  __syncthreads();

  int i0 = t * 8;
  int f[8], cv[8];
  int lsum = 0;
  #pragma unroll
  for (int u = 0; u < 8; u++) {
    int i = i0 + u;
    f[u] = (i == 0) ? 0 : (sInd[i] != sInd[i-1]);
    cv[u] = sClc[i];
    lsum += f[u];
  }
  int x = lsum;
  #pragma unroll
  for (int off = 1; off < 64; off <<= 1) {
    int v = __shfl_up(x, off, 64);
    if (lane >= off) x += v;
  }
  if (lane == 63) sWave[wid] = x;
  __syncthreads();
  int base = 0;
  for (int w = 0; w < wid; w++) base += sWave[w];
  int run = base + x - lsum;
  int rid[8];
  #pragma unroll
  for (int u = 0; u < 8; u++) {
    int i = i0 + u;
    run += f[u];
    rid[u] = run;
    sSeg[i] = run;
    if (f[u] || i == 0) seg_start[b*(MAXSEG+1) + run] = i;
  }
  if (t == 255) { nseg[b] = run + 1; seg_start[b*(MAXSEG+1) + run + 1] = SS; }

  #pragma unroll
  for (int u = 0; u < 8; u++) {
    if (cv[u] < 0) {
      atomicAdd(&sAC[rid[u]], 1);
      atomicMin(&sFA[rid[u]], i0 + u);
    }
  }
  __syncthreads();                         // sSeg also complete past here
  allowCnt[b*MAXSEG + t]   = sAC[t];
  firstAllow[b*MAXSEG + t] = sFA[t];

  int psum = 0;
  int p[8];
  #pragma unroll
  for (int u = 0; u < 8; u++) { p[u] = (cv[u] > 0) ? 1 : 0; psum += p[u]; }
  x = psum;
  #pragma unroll
  for (int off = 1; off < 64; off <<= 1) {
    int v = __shfl_up(x, off, 64);
    if (lane >= off) x += v;
  }
  __syncthreads();
  if (lane == 63) sWave[wid] = x;
  __syncthreads();
  base = 0;
  for (int w = 0; w < wid; w++) base += sWave[w];
  int rank = base + x - psum;
  #pragma unroll
  for (int u = 0; u < 8; u++) {
    if (p[u]) {
      int L = cv[u];                       // label position, 1..SS-1
      int4 rec;
      rec.x = rid[u];                      // si  = segment of this position
      rec.y = sSeg[L];                     // sL  = segment of label position
      rec.z = L;                           // label position
      rec.w = sClc[L];                     // clc at label position (mask test)
      pos_rec[b*PPB + rank] = rec;
      rank++;
    }
  }
  if (t == 255) pos_cnt[b] = rank;
}

// ---------------------------------------------------------------------------
// D2: segment sums. 1024 threads/block: 4 groups of 256 threads, each group
// sums a contiguous quarter of the segment's rows (4-row unrolled), then a
// deterministic 4-way LDS combine. (verified round 5)
// ---------------------------------------------------------------------------
__global__ __launch_bounds__(1024) void k_segsum(
    const float* __restrict__ es,
    const int* __restrict__ seg_start, const int* __restrict__ nseg,
    _Float16* __restrict__ segsum_h)
{
  __shared__ float sP[4][HH];            // 12 KB
  int blk = blockIdx.x, t = threadIdx.x;
  int b = blk >> 8, s = blk & 255;
  _Float16* o = segsum_h + ((size_t)b*MAXSEG + s)*HH;
  if (s >= nseg[b]) {   // zero-fill missing segments (keep downstream NaN-free)
    if (t < HH) o[t] = (_Float16)0.f;
    return;
  }
  int g = t >> 8, tt = t & 255;          // group 0..3, col-thread 0..255
  int st = seg_start[b*(MAXSEG+1) + s];
  int en = seg_start[b*(MAXSEG+1) + s + 1];
  int len = en - st;
  int q = (len + 3) >> 2;                // rows per group (last may be short)
  int gs = st + g*q;
  int ge = gs + q; if (ge > en) ge = en;
  const float* base = es + (size_t)b*SS*HH;
  float a0 = 0.f, a1 = 0.f, a2 = 0.f;
  float b0 = 0.f, b1 = 0.f, b2 = 0.f;
  float c0 = 0.f, c1 = 0.f, c2 = 0.f;
  float d0 = 0.f, d1 = 0.f, d2 = 0.f;
  int i = gs;
  for (; i + 4 <= ge; i += 4) {
    const float* r0 = base + (size_t)i*HH;
    const float* r1 = r0 + HH;
    const float* r2 = r1 + HH;
    const float* r3 = r2 + HH;
    a0 += r0[tt]; a1 += r0[tt+256]; a2 += r0[tt+512];
    b0 += r1[tt]; b1 += r1[tt+256]; b2 += r1[tt+512];
    c0 += r2[tt]; c1 += r2[tt+256]; c2 += r2[tt+512];
    d0 += r3[tt]; d1 += r3[tt+256]; d2 += r3[tt+512];
  }
  for (; i < ge; i++) {
    const float* r = base + (size_t)i*HH;
    a0 += r[tt]; a1 += r[tt+256]; a2 += r[tt+512];
  }
  sP[g][tt]     = (a0 + b0) + (c0 + d0);
  sP[g][tt+256] = (a1 + b1) + (c1 + d1);
  sP[g][tt+512] = (a2 + b2) + (c2 + d2);
  __syncthreads();
  if (t < HH) {
    float v = (sP[0][t] + sP[1][t]) + (sP[2][t] + sP[3][t]);
    o[t] = (_Float16)v;
  }
}

// ---------------------------------------------------------------------------
// D3: U = tanh(segsum @ W^T + bias), f16 MFMA, direct-global fragments.
// 256 blocks x 3 waves = 768 tiles -> all 256 CUs active. (verified round 5)
// ---------------------------------------------------------------------------
__global__ __launch_bounds__(192) void k_gemmU(
    const _Float16* __restrict__ Ah, const _Float16* __restrict__ Wh,
    const float* __restrict__ bias, _Float16* __restrict__ Uh)
{
  int tid = threadIdx.x;
  int w = tid >> 6, lane = tid & 63;
  int tile = blockIdx.x*3 + w;          // 0..767 over 32 x 24 tiles
  int tm = tile / 24, tn = tile % 24;
  int rb = tm*32, cb = tn*32;
  int m0 = lane & 15, quad = lane >> 4;
  const _Float16* A0 = Ah + (size_t)(rb + m0)*HH + quad*8;
  const _Float16* A1 = A0 + (size_t)16*HH;
  const _Float16* B0 = Wh + (size_t)(cb + m0)*HH + quad*8;
  const _Float16* B1 = B0 + (size_t)16*HH;
  f32x4 acc00 = {0.f,0.f,0.f,0.f}, acc01 = {0.f,0.f,0.f,0.f};
  f32x4 acc10 = {0.f,0.f,0.f,0.f}, acc11 = {0.f,0.f,0.f,0.f};
  #pragma unroll 4
  for (int k0 = 0; k0 < HH; k0 += 32) {
    f16x8 a0 = *(const f16x8*)(A0 + k0);
    f16x8 a1 = *(const f16x8*)(A1 + k0);
    f16x8 b0 = *(const f16x8*)(B0 + k0);
    f16x8 b1 = *(const f16x8*)(B1 + k0);
    acc00 = __builtin_amdgcn_mfma_f32_16x16x32_f16(a0, b0, acc00, 0, 0, 0);
    acc01 = __builtin_amdgcn_mfma_f32_16x16x32_f16(a0, b1, acc01, 0, 0, 0);
    acc10 = __builtin_amdgcn_mfma_f32_16x16x32_f16(a1, b0, acc10, 0, 0, 0);
    acc11 = __builtin_amdgcn_mfma_f32_16x16x32_f16(a1, b1, acc11, 0, 0, 0);
  }
  float bc0 = bias[cb + m0], bc1 = bias[cb + 16 + m0];
  int r0 = rb + quad*4;
  #pragma unroll
  for (int i = 0; i < 4; i++) {
    Uh[(size_t)(r0+i)*HH    + cb + m0]      = (_Float16)tanhf(acc00[i] + bc0);
    Uh[(size_t)(r0+i)*HH    + cb + 16 + m0] = (_Float16)tanhf(acc01[i] + bc1);
    Uh[(size_t)(r0+16+i)*HH + cb + m0]      = (_Float16)tanhf(acc10[i] + bc0);
    Uh[(size_t)(r0+16+i)*HH + cb + 16 + m0] = (_Float16)tanhf(acc11[i] + bc1);
  }
}

// ---------------------------------------------------------------------------
// D4: Gram G[b] = U[b] U[b]^T, f16 MFMA. Wave = one 16x16 tile.
// 1024 waves -> 256 blocks. FULL CHIP WIDTH — fusing gram+lse into 64 blocks
// regressed twice (r2 +10us, r6 +13us): 64 blocks = 64 CUs = 1/4 of the
// chip's L2 request bandwidth and MFMA pipes, regardless of waves/CU.
// ---------------------------------------------------------------------------
__global__ __launch_bounds__(256) void k_gram(
    const _Float16* __restrict__ Uh, float* __restrict__ G)
{
  int tid = threadIdx.x;
  int w = tid >> 6, lane = tid & 63;
  int tile = blockIdx.x*4 + w;          // 0..1023
  int b = tile >> 8, rem = tile & 255;
  int rb = (rem >> 4)*16, cb = (rem & 15)*16;
  int m0 = lane & 15, quad = lane >> 4;
  const _Float16* Ub = Uh + (size_t)b*MAXSEG*HH;
  const _Float16* A0 = Ub + (size_t)(rb + m0)*HH + quad*8;
  const _Float16* B0 = Ub + (size_t)(cb + m0)*HH + quad*8;
  f32x4 acc = {0.f,0.f,0.f,0.f};
  #pragma unroll 4
  for (int k0 = 0; k0 < HH; k0 += 32) {
    f16x8 a  = *(const f16x8*)(A0 + k0);
    f16x8 bb = *(const f16x8*)(B0 + k0);
    acc = __builtin_amdgcn_mfma_f32_16x16x32_f16(a, bb, acc, 0, 0, 0);
  }
  float* Gb = G + (size_t)b*MAXSEG*MAXSEG;
  int r0 = rb + quad*4;
  #pragma unroll
  for (int i = 0; i < 4; i++)
    Gb[(size_t)(r0+i)*MAXSEG + cb + m0] = acc[i];
}

// ---------------------------------------------------------------------------
// D5: per (b,seg) row: masked logsumexp + first-occurrence argmax.
// Vectorized float4/int4 loads. (verified round 5)
// ---------------------------------------------------------------------------
__global__ __launch_bounds__(256) void k_seglse(
    const float* __restrict__ G, const int* __restrict__ allowCnt,
    const int* __restrict__ firstAllow, const int* __restrict__ nseg,
    float* __restrict__ lse, int* __restrict__ amax)
{
  int lane = threadIdx.x & 63, wid = threadIdx.x >> 6;
  int row = blockIdx.x * 4 + wid;
  int b = row >> 8, si = row & 255;
  if (si >= nseg[b]) return;
  const float* g = G + ((size_t)b*MAXSEG + si)*MAXSEG;
  const int* ac = allowCnt + b*MAXSEG;
  const int* fa = firstAllow + b*MAXSEG;

  float4 gv = ((const float4*)g)[lane];
  int4   av = ((const int4*)ac)[lane];
  int4   fv = ((const int4*)fa)[lane];
  float gvv[4] = {gv.x, gv.y, gv.z, gv.w};
  int   avv[4] = {av.x, av.y, av.z, av.w};
  int   fvv[4] = {fv.x, fv.y, fv.z, fv.w};

  float m = -INFINITY;
  #pragma unroll
  for (int q = 0; q < 4; q++) if (avv[q] > 0) m = fmaxf(m, gvv[q]);
  #pragma unroll
  for (int off = 32; off > 0; off >>= 1) m = fmaxf(m, __shfl_xor(m, off, 64));
  float s = 0.f;
  #pragma unroll
  for (int q = 0; q < 4; q++) if (avv[q] > 0) s += (float)avv[q] * expf(gvv[q] - m);
  #pragma unroll
  for (int off = 32; off > 0; off >>= 1) s += __shfl_xor(s, off, 64);
  float bv = -INFINITY; int bi = INT_MAX;
  #pragma unroll
  for (int q = 0; q < 4; q++) {
    if (avv[q] > 0 && (gvv[q] > bv || (gvv[q] == bv && fvv[q] < bi))) { bv = gvv[q]; bi = fvv[q]; }
  }
  #pragma unroll
  for (int off = 32; off > 0; off >>= 1) {
    float ov = __shfl_xor(bv, off, 64);
    int   oi = __shfl_xor(bi, off, 64);
    if (ov > bv || (ov == bv && oi < bi)) { bv = ov; bi = oi; }
  }
  if (lane == 0) {
    lse[row]  = m + logf(s);
    amax[row] = bi;
  }
}

// ---------------------------------------------------------------------------
// D6: single block — all positives via packed records (2-level gather:
// coalesced 16B record load -> G/lse/amax). (verified round 6)
// ---------------------------------------------------------------------------
__global__ __launch_bounds__(256) void k_posfinal(
    const float* __restrict__ G, const int4* __restrict__ pos_rec,
    const int* __restrict__ pos_cnt, const float* __restrict__ lse,
    const int* __restrict__ amax, float* __restrict__ out)
{
  __shared__ int sBase[BB+1];
  __shared__ float sL0[4], sC0[4], sL1[4], sC1[4];
  int t = threadIdx.x;
  if (t == 0) {
    int acc = 0; sBase[0] = 0;
    for (int b = 0; b < BB; b++) { acc += pos_cnt[b]; sBase[b+1] = acc; }
  }
  __syncthreads();
  int total = sBase[BB];
  if (total > NUM_POS) total = NUM_POS;

  int rs[8]; bool ok[8]; int bv[8];
  #pragma unroll
  for (int u = 0; u < 8; u++) {
    rs[u] = t + 256*u;
    ok[u] = rs[u] < total;
    int b = 0;
    if (ok[u]) { while (b < BB-1 && rs[u] >= sBase[b+1]) b++; }
    bv[u] = b;
  }
  int4 rec[8];
  #pragma unroll
  for (int u = 0; u < 8; u++) {
    rec[u] = ok[u] ? pos_rec[bv[u]*PPB + (rs[u] - sBase[bv[u]])]
                   : make_int4(0, 0, 0, 0);
  }
  float gv[8], lv[8]; int av[8];
  #pragma unroll
  for (int u = 0; u < 8; u++) {
    gv[u] = ok[u] ? G[((size_t)bv[u]*MAXSEG + rec[u].x)*MAXSEG + rec[u].y] : 0.f;
    lv[u] = ok[u] ? lse[bv[u]*MAXSEG + rec[u].x] : 0.f;
    av[u] = ok[u] ? amax[bv[u]*MAXSEG + rec[u].x] : -1;
  }

  float l0 = 0.f, c0 = 0.f, l1 = 0.f, c1 = 0.f;
  #pragma unroll
  for (int u = 0; u < 8; u++) {
    if (!ok[u]) continue;
    float vL = gv[u] + (rec[u].w < 0 ? 0.0f : NEG_BIG);
    float loss = lv[u] - vL;
    float corr = (av[u] == rec[u].z) ? 1.0f : 0.0f;
    if (rs[u] & 1) { l1 += loss; c1 += corr; } else { l0 += loss; c0 += corr; }
  }

  int lane = t & 63, wid = t >> 6;
  #pragma unroll
  for (int off = 32; off > 0; off >>= 1) {
    l0 += __shfl_down(l0, off, 64);
    c0 += __shfl_down(c0, off, 64);
    l1 += __shfl_down(l1, off, 64);
    c1 += __shfl_down(c1, off, 64);
  }
  if (lane == 0) { sL0[wid] = l0; sC0[wid] = c0; sL1[wid] = l1; sC1[wid] = c1; }
  __syncthreads();
  if (t == 0) {
    float L0 = sL0[0]+sL0[1]+sL0[2]+sL0[3];
    float C0 = sC0[0]+sC0[1]+sC0[2]+sC0[3];
    float L1 = sL1[0]+sL1[1]+sL1[2]+sL1[3];
    float C1 = sC1[0]+sC1[1]+sC1[2]+sC1[3];
    float n = (float)(NUM_POS/2);   // 1024
    out[0] = L0 / n;
    out[1] = C0;
    out[2] = n + 1e-6f;
    out[3] = L1 / n;
    out[4] = C1;
    out[5] = n + 1e-6f;
  }
}

// ---------------------------------------------------------------------------
extern "C" void kernel_launch(void* const* d_in, const int* in_sizes, int n_in,
                              void* d_out, int out_size, void* d_ws, size_t ws_size,
                              hipStream_t stream)
{
  const float* es   = (const float*)d_in[0];
  const float* W    = (const float*)d_in[1];
  const float* bias = (const float*)d_in[2];
  const int*   ind  = (const int*)d_in[3];
  const int*   clc  = (const int*)d_in[4];
  float* out = (float*)d_out;

  char* ws = (char*)d_ws;
  int*   nseg       = (int*)(ws + 0);
  int*   pos_cnt    = (int*)(ws + 256);
  int*   seg_start  = (int*)(ws + 1024);                 // B*(MAXSEG+1)
  int4*  pos_rec    = (int4*)(ws + 40960);               // B*512*16 = 32 KB
  int*   allowCnt   = (int*)(ws + 73728);                // B*256
  int*   firstAllow = (int*)(ws + 77824);
  float* lse        = (float*)(ws + 81920);
  int*   amax       = (int*)(ws + 86016);
  _Float16* segsum_h = (_Float16*)(ws + 90112);          // 1024*768*2 = 1.5 MB
  _Float16* Wh       = (_Float16*)(ws + 1662976);        // 768*768*2 = 1.125 MB
  _Float16* Uh       = (_Float16*)(ws + 2842624);        // 1.5 MB
  float*    G        = (float*)(ws + 4415488);           // 1 MB

  k_scanW<<<BB + 576, 256, 0, stream>>>(ind, clc, W, Wh, seg_start,
                                        nseg, pos_rec, pos_cnt, allowCnt, firstAllow);
  k_segsum<<<BB*MAXSEG, 1024, 0, stream>>>(es, seg_start, nseg, segsum_h);
  k_gemmU<<<256, 192, 0, stream>>>(segsum_h, Wh, bias, Uh);
  k_gram<<<256, 256, 0, stream>>>(Uh, G);
  k_seglse<<<(BB*MAXSEG)/4, 256, 0, stream>>>(G, allowCnt, firstAllow, nseg, lse, amax);
  k_posfinal<<<1, 256, 0, stream>>>(G, pos_rec, pos_cnt, lse, amax, out);
}